// Round 1
// baseline (301.432 us; speedup 1.0000x reference)
//
#include <hip/hip_runtime.h>
#include <hip/hip_bf16.h>

#define NN 4
#define LL 8192
#define HH 8
#define DD 64
#define NH 32                 // n*h combos
#define ROW_STRIDE (HH*DD)    // 512 floats between consecutive s rows
#define TILE 16
#define LDS_PAD 68            // row stride in LDS floats (272 B -> balanced b128 writes)
#define KV_ELEMS 4160         // 65*64 (64x64 KV + ksum row)

__device__ __forceinline__ float phi(float x) {
  // elu(x*temp) + 1 ; temp = 64^(-0.25) = 0.353553390593...
  float t = x * 0.35355339059327373f;
  return t > 0.f ? t + 1.f : __expf(t);
}

// ---------------- Kernel A: partial KV (and ksum) over s-chunks ----------------
// lane = d. Each lane accumulates KV[m][d_lane] for m=0..63 in 64 VGPRs.
// k[s][d_lane] read per-lane coalesced from global, phi applied in-register.
// v rows staged raw in per-wave LDS region, consumed via broadcast ds_read_b128.
__global__ __launch_bounds__(256) void kv_partial_kernel(
    const float* __restrict__ K, const float* __restrict__ V,
    float* __restrict__ part, int nchunk)
{
  const int nh    = blockIdx.x / nchunk;
  const int chunk = blockIdx.x % nchunk;
  const int n = nh >> 3, h = nh & 7;
  const int tid = threadIdx.x;
  const int w = tid >> 6, lane = tid & 63;
  const int rows_per_block = LL / nchunk;
  const int rows_per_wave  = rows_per_block >> 2;
  const int s_begin = chunk * rows_per_block + w * rows_per_wave;

  const float* kbase = K + ((size_t)n * LL * HH + h) * DD;
  const float* vbase = V + ((size_t)n * LL * HH + h) * DD;

  __shared__ float v_lds[4][TILE * LDS_PAD];

  float acc[64];
#pragma unroll
  for (int m = 0; m < 64; ++m) acc[m] = 0.f;
  float ksum = 0.f;

  const int lr = lane >> 2, seg = lane & 3;   // 4 lanes per staged row

  for (int t0 = 0; t0 < rows_per_wave; t0 += TILE) {
    const int s0 = s_begin + t0;

    // ---- stage V tile (raw copy), 16 rows x 64 floats, per-wave region ----
    const float* vrow = vbase + (size_t)(s0 + lr) * ROW_STRIDE;
    float* vl = &v_lds[w][lr * LDS_PAD];
#pragma unroll
    for (int i = 0; i < 4; ++i) {
      const int c = i * 16 + seg * 4;          // lanes 0..3 cover 64B contiguous
      float4 vv = *(const float4*)(vrow + c);
      *(float4*)(vl + c) = vv;
    }

    // ---- K column for this lane (d = lane), 16 rows, coalesced dwords ----
    float kreg[TILE];
    const float* kcol = kbase + lane;
#pragma unroll
    for (int j = 0; j < TILE; ++j)
      kreg[j] = kcol[(size_t)(s0 + j) * ROW_STRIDE];
#pragma unroll
    for (int j = 0; j < TILE; ++j)
      kreg[j] = phi(kreg[j]);

    // ---- accumulate outer products ----
#pragma unroll
    for (int j = 0; j < TILE; ++j) {
      const float kf = kreg[j];
      ksum += kf;
      const float* vr = &v_lds[w][j * LDS_PAD];
#pragma unroll
      for (int m = 0; m < 64; m += 4) {
        float4 vv = *(const float4*)(vr + m);   // broadcast b128 (uniform addr)
        acc[m+0] += vv.x * kf;
        acc[m+1] += vv.y * kf;
        acc[m+2] += vv.z * kf;
        acc[m+3] += vv.w * kf;
      }
    }
  }

  // ---- write this wave's partial: p = blockIdx.x*4 + w (nh-major) ----
  float* o = part + ((size_t)blockIdx.x * 4 + w) * KV_ELEMS;
#pragma unroll
  for (int m = 0; m < 64; ++m) o[m * 64 + lane] = acc[m];   // [m][d] coalesced
  o[4096 + lane] = ksum;
}

// ---------------- Kernel B: reduce partials -> final KV + ksum per nh ----------------
__global__ __launch_bounds__(256) void kv_reduce_kernel(
    const float* __restrict__ part, float* __restrict__ kvf, int np)
{
  const int nh = blockIdx.x / 17;
  const int ec = blockIdx.x % 17;
  const int e = ec * 256 + threadIdx.x;
  if (e >= KV_ELEMS) return;
  const float* p = part + (size_t)nh * np * KV_ELEMS + e;
  float s = 0.f;
  for (int i = 0; i < np; ++i) s += p[(size_t)i * KV_ELEMS];
  kvf[(size_t)nh * KV_ELEMS + e] = s;
}

// ---------------- Kernel C: out[l][m] = z_l * (phi(q)_l . KV[m][:]) ----------------
// lane = m. KV row in 64 VGPRs; phi(q) tile staged in per-wave LDS;
// z via per-lane product with ksum[lane] + butterfly reduce (independent of matvec).
__global__ __launch_bounds__(256) void attn_out_kernel(
    const float* __restrict__ Q, const float* __restrict__ kvf,
    float* __restrict__ out, int nlchunk)
{
  const int nh    = blockIdx.x / nlchunk;
  const int chunk = blockIdx.x % nlchunk;
  const int n = nh >> 3, h = nh & 7;
  const int tid = threadIdx.x;
  const int w = tid >> 6, lane = tid & 63;
  const int rows_per_block = LL / nlchunk;
  const int rows_per_wave  = rows_per_block >> 2;
  const int row_begin = chunk * rows_per_block + w * rows_per_wave;

  const float* qbase = Q + ((size_t)n * LL * HH + h) * DD;
  const float* kvb   = kvf + (size_t)nh * KV_ELEMS;

  // KV[lane][d] into registers (L2-resident, small)
  float kv[64];
#pragma unroll
  for (int d = 0; d < 64; d += 4) {
    float4 t = *(const float4*)(kvb + lane * 64 + d);
    kv[d] = t.x; kv[d+1] = t.y; kv[d+2] = t.z; kv[d+3] = t.w;
  }
  const float ks = kvb[4096 + lane];

  __shared__ float q_lds[4][TILE * LDS_PAD];
  const int lr = lane >> 2, seg = lane & 3;

  for (int t0 = 0; t0 < rows_per_wave; t0 += TILE) {
    const int r0 = row_begin + t0;

    // ---- stage phi(Q) tile ----
    const float* qrow = qbase + (size_t)(r0 + lr) * ROW_STRIDE;
    float* ql = &q_lds[w][lr * LDS_PAD];
#pragma unroll
    for (int i = 0; i < 4; ++i) {
      const int c = i * 16 + seg * 4;
      float4 qv = *(const float4*)(qrow + c);
      qv.x = phi(qv.x); qv.y = phi(qv.y); qv.z = phi(qv.z); qv.w = phi(qv.w);
      *(float4*)(ql + c) = qv;
    }

    // ---- per row: z + matvec ----
#pragma unroll
    for (int j = 0; j < TILE; ++j) {
      const float* qr = &q_lds[w][j * LDS_PAD];

      // z denominator: per-lane product + butterfly (scheduler hides under matvec)
      float p = qr[lane] * ks;
#pragma unroll
      for (int off = 32; off; off >>= 1) p += __shfl_xor(p, off, 64);
      const float z = 1.0f / (p + 1e-6f);

      float a = 0.f;
#pragma unroll
      for (int d = 0; d < 64; d += 4) {
        float4 q4 = *(const float4*)(qr + d);   // broadcast b128
        a += q4.x * kv[d]   + q4.y * kv[d+1]
           + q4.z * kv[d+2] + q4.w * kv[d+3];
      }

      const int row = r0 + j;
      out[((size_t)nh * LL + row) * DD + lane] = a * z;  // coalesced
    }
  }
}

extern "C" void kernel_launch(void* const* d_in, const int* in_sizes, int n_in,
                              void* d_out, int out_size, void* d_ws, size_t ws_size,
                              hipStream_t stream)
{
  const float* Q = (const float*)d_in[0];
  const float* K = (const float*)d_in[1];
  const float* V = (const float*)d_in[2];
  float* out = (float*)d_out;
  float* ws  = (float*)d_ws;

  // pick largest nchunk whose partial buffer fits the workspace
  int nchunk = 16;
  while (nchunk > 1) {
    size_t need = ((size_t)NH * nchunk * 4 + NH) * KV_ELEMS * sizeof(float);
    if (need <= ws_size) break;
    nchunk >>= 1;
  }
  float* part = ws;
  float* kvf  = ws + (size_t)NH * nchunk * 4 * KV_ELEMS;

  hipLaunchKernelGGL(kv_partial_kernel, dim3(NH * nchunk), dim3(256), 0, stream,
                     K, V, part, nchunk);
  hipLaunchKernelGGL(kv_reduce_kernel, dim3(NH * 17), dim3(256), 0, stream,
                     part, kvf, nchunk * 4);
  hipLaunchKernelGGL(attn_out_kernel, dim3(NH * 64), dim3(256), 0, stream,
                     Q, kvf, out, 64);
}